// Round 14
// baseline (203.568 us; speedup 1.0000x reference)
//
#include <hip/hip_runtime.h>
#include <hip/hip_fp16.h>

typedef unsigned short u16;
typedef __attribute__((ext_vector_type(8))) _Float16 h8;
typedef __attribute__((ext_vector_type(2))) _Float16 h2;
typedef __attribute__((ext_vector_type(2))) __fp16 fp16x2;
typedef __attribute__((ext_vector_type(8))) short s16x8;
typedef __attribute__((ext_vector_type(4))) float fx4;
typedef __attribute__((ext_vector_type(16))) float f32x16;
typedef __attribute__((ext_vector_type(2))) unsigned int u32x2;

#define MFMA16(a,b,c) __builtin_amdgcn_mfma_f32_16x16x32_f16((a),(b),(c),0,0,0)
#define MFMA32(a,b,c) __builtin_amdgcn_mfma_f32_32x32x16_f16((a),(b),(c),0,0,0)

#if __has_builtin(__builtin_amdgcn_exp2f)
#define EXP2(x) __builtin_amdgcn_exp2f(x)
#else
#define EXP2(x) exp2f(x)
#endif

#if __has_builtin(__builtin_amdgcn_global_load_lds)
#define HAS_GLL 1
// async global->LDS, 16B per lane. LDS dest = wave-uniform base + lane*16 (HW).
static __device__ __forceinline__ void gll16(const u16* g, const u16* l){
  __builtin_amdgcn_global_load_lds(
      (const __attribute__((address_space(1))) void*)g,
      (__attribute__((address_space(3))) void*)(uint32_t)(uintptr_t)(const void*)l,
      16, 0, 0);
}
#else
#define HAS_GLL 0
#endif

static __device__ __forceinline__ u16 f2hbits(float x){
  __half h = __float2half_rn(x);
  union { __half h; u16 u; } c; c.h = h; return c.u;
}
static __device__ __forceinline__ uint32_t pkh(float a, float b){
#if __has_builtin(__builtin_amdgcn_cvt_pkrtz)
  union { fp16x2 h; uint32_t u; } c;
  c.h = __builtin_amdgcn_cvt_pkrtz(a, b);
  return c.u;
#else
  __half2 h = __floats2half2_rn(a, b);
  union { __half2 h; uint32_t u; } c; c.h = h; return c.u;
#endif
}
// l += pk.lo + pk.hi  via v_dot2_f32_f16 (sums the exact fp16 P used by PV)
static __device__ __forceinline__ float dot2h(uint32_t u, float c){
  union { uint32_t x; h2 h; } cv; cv.x = u;
  h2 one; one[0] = (_Float16)1.0f; one[1] = (_Float16)1.0f;
  return __builtin_amdgcn_fdot2(cv.h, one, c, false);
}

// ---------------- prep: fp32 -> fp16 cast ----------------
__global__ void f2h_kernel(const float* __restrict__ in, u16* __restrict__ out, int n4){
  int i = blockIdx.x*256 + threadIdx.x;
  if (i < n4){
    float4 v = ((const float4*)in)[i];
    ushort4 o;
    o.x = f2hbits(v.x); o.y = f2hbits(v.y); o.z = f2hbits(v.z); o.w = f2hbits(v.w);
    ((ushort4*)out)[i] = o;
  }
}

// ---------------- prep: W[h][n][d] -> Wt[h*64+d][n] fp16 ----------------
__global__ void wtr_kernel(const float* __restrict__ Wq, const float* __restrict__ Wk,
                           const float* __restrict__ Wv, u16* __restrict__ Wt){
  __shared__ float tl[64][65];
  int z = blockIdx.z, h = blockIdx.y, n0 = blockIdx.x*64;
  const float* W = (z==0)?Wq:((z==1)?Wk:Wv);
  W += (size_t)h*65536;  // h * 1024 * 64
  int t = threadIdx.x;
  #pragma unroll
  for (int i=0;i<16;++i){
    int idx = t + i*256; int r = idx>>6, c = idx&63;
    tl[r][c] = W[(size_t)(n0+r)*64 + c];
  }
  __syncthreads();
  u16* O = Wt + (size_t)z*1048576 + (size_t)h*64*1024 + n0;
  #pragma unroll
  for (int i=0;i<16;++i){
    int idx = t + i*256; int r2 = idx>>6, c2 = idx&63;
    O[(size_t)r2*1024 + c2] = f2hbits(tl[c2][r2]);
  }
}

// ---------------- 128x128x(K=1024) NT GEMM, fp16 MFMA ----------------
// Staging via global_load_lds width=16 (async direct-to-LDS, m97 schedule).
// EPI==0 epilogue writes Q/K/V in MFMA-FRAGMENT-PACKED layout; Q pre-scaled
// by 0.125*log2(e) (attention softmax runs in log2 domain).
template<int EPI>
__launch_bounds__(256, 2)
__global__ void gemm_nt(const u16* __restrict__ A, const u16* __restrict__ Bbase,
                        const float* __restrict__ bias0, const float* __restrict__ bias1,
                        const float* __restrict__ bias2,
                        u16* __restrict__ out0, u16* __restrict__ out1, u16* __restrict__ out2,
                        float* __restrict__ fout){
  __shared__ __align__(16) u16 lds[16384];
  const int K = 1024;
  int mt = blockIdx.x, ntile = blockIdx.y, z = blockIdx.z;
  int m0 = mt*128, n0 = ntile*128;
  const u16* Ap = A;
  const u16* Bp = (EPI==0) ? (Bbase + (size_t)z*1048576) : (Bbase + (size_t)z*2097152);
  int t = threadIdx.x;
  int lane = t & 63, wv = t>>6, g = lane>>4, q15 = lane&15;
  int wr = wv>>1, wc = wv&1;

  fx4 zero4 = {0.f,0.f,0.f,0.f};
  fx4 acc[4][4];
  #pragma unroll
  for (int i=0;i<4;++i)
    #pragma unroll
    for (int j=0;j<4;++j) acc[i][j] = zero4;

  int rowA = t>>2, col8 = (t&3)*8;
  const u16* gA0 = Ap + (size_t)(m0+rowA)*K + col8;
  const u16* gA1 = Ap + (size_t)(m0+rowA+64)*K + col8;
  const u16* gB0 = Bp + (size_t)(n0+rowA)*K + col8;
  const u16* gB1 = Bp + (size_t)(n0+rowA+64)*K + col8;
  int cur = 0;

#if HAS_GLL
  u16* st = lds + wv*512;         // wave-uniform region base (HW adds lane*16B)
  {
    gll16(gA0, st);
    gll16(gA1, st + 2048);
    gll16(gB0, st + 4096);
    gll16(gB1, st + 6144);
  }
  for (int kt=0; kt<32; ++kt){
    __syncthreads();              // drains vmcnt: buf[cur] ready
    if (kt+1 < 32){
      int k0 = (kt+1)*32;
      u16* nb = st + (cur^1)*8192;
      gll16(gA0 + k0, nb);
      gll16(gA1 + k0, nb + 2048);
      gll16(gB0 + k0, nb + 4096);
      gll16(gB1 + k0, nb + 6144);
    }
    const u16* bufA = lds + cur*8192;
    const u16* bufB = bufA + 4096;
    h8 af[4], bf[4];
    #pragma unroll
    for (int f=0; f<4; ++f)
      af[f] = *(const h8*)(bufA + (wr*64 + f*16 + q15)*32 + g*8);
    #pragma unroll
    for (int f=0; f<4; ++f)
      bf[f] = *(const h8*)(bufB + (wc*64 + f*16 + q15)*32 + g*8);
    #pragma unroll
    for (int i=0;i<4;++i)
      #pragma unroll
      for (int j=0;j<4;++j)
        acc[i][j] = MFMA16(af[i], bf[j], acc[i][j]);
    cur ^= 1;
  }
#else
  s16x8 sa0 = *(const s16x8*)(gA0);
  s16x8 sa1 = *(const s16x8*)(gA1);
  s16x8 sb0 = *(const s16x8*)(gB0);
  s16x8 sb1 = *(const s16x8*)(gB1);
  *(s16x8*)(lds + t*8)        = sa0;
  *(s16x8*)(lds + 2048 + t*8) = sa1;
  *(s16x8*)(lds + 4096 + t*8) = sb0;
  *(s16x8*)(lds + 6144 + t*8) = sb1;
  for (int kt=0; kt<32; ++kt){
    if (kt+1 < 32){
      int k0 = (kt+1)*32;
      sa0 = *(const s16x8*)(gA0 + k0);
      sa1 = *(const s16x8*)(gA1 + k0);
      sb0 = *(const s16x8*)(gB0 + k0);
      sb1 = *(const s16x8*)(gB1 + k0);
    }
    __syncthreads();
    const u16* bufA = lds + cur*8192;
    const u16* bufB = bufA + 4096;
    h8 af[4], bf[4];
    #pragma unroll
    for (int f=0; f<4; ++f)
      af[f] = *(const h8*)(bufA + (wr*64 + f*16 + q15)*32 + g*8);
    #pragma unroll
    for (int f=0; f<4; ++f)
      bf[f] = *(const h8*)(bufB + (wc*64 + f*16 + q15)*32 + g*8);
    #pragma unroll
    for (int i=0;i<4;++i)
      #pragma unroll
      for (int j=0;j<4;++j)
        acc[i][j] = MFMA16(af[i], bf[j], acc[i][j]);
    if (kt+1 < 32){
      u16* nb = lds + (cur^1)*8192;
      *(s16x8*)(nb + t*8)        = sa0;
      *(s16x8*)(nb + 2048 + t*8) = sa1;
      *(s16x8*)(nb + 4096 + t*8) = sb0;
      *(s16x8*)(nb + 6144 + t*8) = sb1;
      cur ^= 1;
    }
  }
#endif

  if constexpr (EPI==0){
    const float* bias = (z==0)?bias0:((z==1)?bias1:bias2);
    float bcol[4];
    #pragma unroll
    for (int fj=0;fj<4;++fj) bcol[fj] = bias[n0 + wc*64 + fj*16 + q15];
    int bb = m0 >> 11;            // batch (tiles never cross batch)
    int s_base = (m0 & 2047) + wr*64;
    if (z < 2){
      u16* o = (z==0)? out0 : out1;
      float sc = (z==0)? 0.180336880f : 1.0f;   // Q: 0.125 * log2(e)
      #pragma unroll
      for (int fi=0;fi<4;++fi)
        #pragma unroll
        for (int fj=0;fj<4;++fj){
          int n = n0 + wc*64 + fj*16 + q15;
          int hh = n>>6, d = n&63;
          int sf = d>>4, h2i = (d>>3)&1, j = d&7;
          size_t base = ((size_t)(bb*16+hh)<<17);
          #pragma unroll
          for (int r=0;r<4;++r){
            int s = s_base + fi*16 + g*4 + r;
            int kt2 = s>>5, l = s&31;
            float v = (acc[fi][fj][r] + bcol[fj]) * sc;
            o[base + (((size_t)((kt2*8 + sf*2 + h2i)*32 + l))<<3) + j] = f2hbits(v);
          }
        }
    } else {
      // V fragment-packed
      #pragma unroll
      for (int fi=0;fi<4;++fi)
        #pragma unroll
        for (int fj=0;fj<4;++fj){
          int n = n0 + wc*64 + fj*16 + q15;
          int hh = n>>6, d = n&63;
          size_t base = ((size_t)(bb*16+hh)<<17);
          int kt2 = (s_base + fi*16)>>5;
          int tt = fi & 1;
          int h2v = g>>1;
          int jv = (g&1)*4;
          ushort4 pk;
          pk.x = f2hbits(acc[fi][fj][0] + bcol[fj]);
          pk.y = f2hbits(acc[fi][fj][1] + bcol[fj]);
          pk.z = f2hbits(acc[fi][fj][2] + bcol[fj]);
          pk.w = f2hbits(acc[fi][fj][3] + bcol[fj]);
          *(ushort4*)(out2 + base + (((size_t)((kt2*4 + tt*2 + h2v)*64 + d))<<3) + jv) = pk;
        }
    }
  } else {
    int bb = z;
    float brow[4][4];
    #pragma unroll
    for (int fi=0;fi<4;++fi)
      #pragma unroll
      for (int r=0;r<4;++r) brow[fi][r] = bias0[m0 + wr*64 + fi*16 + g*4 + r];
    #pragma unroll
    for (int fi=0;fi<4;++fi)
      #pragma unroll
      for (int fj=0;fj<4;++fj){
        int scol = n0 + wc*64 + fj*16 + q15;
        #pragma unroll
        for (int r=0;r<4;++r){
          int orow = m0 + wr*64 + fi*16 + g*4 + r;
          fout[((size_t)bb<<21) + ((size_t)orow<<11) + scol] = acc[fi][fj][r] + brow[fi][r];
        }
      }
  }
}

// ---------------- flash attention, 32x32 swapped, split-KV in-block ----------
// 256-thr blocks: 4 waves = 2 split-KV pairs (grid 2048). Waves (2p,2p+1)
// share 32 q-rows; wave half=wv&1 sweeps KV tiles [half*32, half*32+32).
// Fixed-max softmax => partials combine LINEARLY (O=Oa+Ob, l=la+lb): one
// 16KB LDS exchange + one __syncthreads at block end, no rescale.
// 4-wave blocks pack better under the VGPR cap than 8-wave: 5 blocks/CU
// (20 waves) vs 2x8=16 -> +25% resident TLP at identical per-wave code.
__launch_bounds__(256)
__global__ void attn_kernel(const u16* __restrict__ Qb, const u16* __restrict__ Kb,
                            const u16* __restrict__ Vt, u16* __restrict__ Ob){
  __shared__ float sO[2][32][64];   // odd-wave partial O   (16 KB)
  __shared__ float sL[2][64];       // odd-wave partial l   (0.5 KB)
  int bid = blockIdx.x;
  int g63 = bid & 63, qg = bid >> 6;     // qg in 0..31: 64-q-row group
  int b = g63 >> 4, h = g63 & 15;
  int t = threadIdx.x;
  int lane = t & 63, wv = t >> 6;        // wv in 0..3
  int pair = wv >> 1, half = wv & 1;
  int l31 = lane&31, hi = lane>>5;
  size_t bh = (size_t)(b*16 + h);
  const u16* Qp = Qb + (bh<<17);   // fragment-packed
  const u16* Kp = Kb + (bh<<17);
  const u16* Vp = Vt + (bh<<17);
  int q0 = qg*64 + pair*32;
  int qt = qg*2 + pair;            // q0>>5
  const float NML2E = -5.77078016f;   // -4*log2(e): fixed-max shift (log2 units)

  // Q fragments (B-operand): col=q=lane&31, k = s*16 + hi*8 + j
  h8 qf[4];
  #pragma unroll
  for (int s=0;s<4;++s)
    qf[s] = *(const h8*)(Qp + (((size_t)((qt*8 + s*2 + hi)*32 + l31))<<3));

  f32x16 o0, o1, sinit;
  #pragma unroll
  for (int i=0;i<16;++i){ o0[i]=0.f; o1[i]=0.f; sinit[i]=NML2E; }
  float l_a = 0.f, l_b = 0.f;

  // this wave's KV half: 32 tiles, starting at tile half*32 (65536 u16 offset)
  const u16* kc = Kp + half*65536 + (hi*256 + l31*8);
  const u16* vc = Vp + half*65536 + (hi*512 + l31*8);

  auto LOADKV = [&](const u16* kp, const u16* vp, h8 (&kf_)[4], h8 (&vf_)[4]) {
    kf_[0] = *(const h8*)(kp);
    kf_[1] = *(const h8*)(kp + 512);
    kf_[2] = *(const h8*)(kp + 1024);
    kf_[3] = *(const h8*)(kp + 1536);
    vf_[0] = *(const h8*)(vp);
    vf_[1] = *(const h8*)(vp + 256);
    vf_[2] = *(const h8*)(vp + 1024);
    vf_[3] = *(const h8*)(vp + 1280);
  };

  auto TILE = [&](h8 (&kf_)[4], h8 (&vf_)[4]) {
    __builtin_amdgcn_s_setprio(1);
    f32x16 S = MFMA32(kf_[0], qf[0], sinit);   // C-operand carries the shift
    S = MFMA32(kf_[1], qf[1], S);
    S = MFMA32(kf_[2], qf[2], S);
    S = MFMA32(kf_[3], qf[3], S);
    __builtin_amdgcn_s_setprio(0);
    // S[i]: kv = (i&3) + 8*(i>>2) + 4*hi (local), q = lane&31, log2 units

    float p[16];
    #pragma unroll
    for (int i=0;i<16;++i) p[i] = EXP2(S[i]);

    #pragma unroll
    for (int tt=0; tt<2; ++tt){
      uint32_t A0 = pkh(p[8*tt+0], p[8*tt+1]);
      uint32_t A1 = pkh(p[8*tt+2], p[8*tt+3]);
      uint32_t B0 = pkh(p[8*tt+4], p[8*tt+5]);
      uint32_t B1 = pkh(p[8*tt+6], p[8*tt+7]);
      l_a = dot2h(A0, dot2h(B0, l_a));
      l_b = dot2h(A1, dot2h(B1, l_b));
      union { uint32_t u[4]; h8 v; } pf;
#if __has_builtin(__builtin_amdgcn_permlane32_swap)
      u32x2 rx = __builtin_amdgcn_permlane32_swap(A0, B0, false, false);
      u32x2 ry = __builtin_amdgcn_permlane32_swap(A1, B1, false, false);
      pf.u[0] = rx[0]; pf.u[1] = ry[0]; pf.u[2] = rx[1]; pf.u[3] = ry[1];
#else
      uint32_t s0 = hi ? A0 : B0, s1 = hi ? A1 : B1;
      uint32_t r0 = __shfl_xor(s0, 32), r1 = __shfl_xor(s1, 32);
      pf.u[0] = hi ? r0 : A0;
      pf.u[1] = hi ? r1 : A1;
      pf.u[2] = hi ? B0 : r0;
      pf.u[3] = hi ? B1 : r1;
#endif
      __builtin_amdgcn_s_setprio(1);
      if (tt == 0){
        o0 = MFMA32(vf_[0], pf.v, o0);
        o1 = MFMA32(vf_[1], pf.v, o1);
      } else {
        o0 = MFMA32(vf_[2], pf.v, o0);
        o1 = MFMA32(vf_[3], pf.v, o1);
      }
      __builtin_amdgcn_s_setprio(0);
    }
  };

  h8 kfA[4], vfA[4], kfB[4], vfB[4];
  LOADKV(kc, vc, kfA, vfA);
  for (int kt=0; kt<32; kt+=2){
    LOADKV(kc+2048, vc+2048, kfB, vfB);
    TILE(kfA, vfA);
    if (kt+2 < 32) LOADKV(kc+4096, vc+4096, kfA, vfA);
    kc += 4096; vc += 4096;
    TILE(kfB, vfB);
  }
  float l_run = l_a + l_b;

  // ---- split-KV combine: odd wave -> LDS; even wave adds, normalizes, stores
  if (half){
    #pragma unroll
    for (int i=0;i<16;++i){
      sO[pair][i][lane]    = o0[i];
      sO[pair][16+i][lane] = o1[i];
    }
    sL[pair][lane] = l_run;
  }
  __syncthreads();
  if (!half){
    #pragma unroll
    for (int i=0;i<16;++i){
      o0[i] += sO[pair][i][lane];
      o1[i] += sO[pair][16+i][lane];
    }
    l_run += sL[pair][lane];
    // cross-half l combine (lane hi halves own disjoint kv), once
    float l_tot = l_run + __shfl_xor(l_run, 32);
    float linv = 1.f / l_tot;
    // o{0,1}[i]: d = 32*dt + (i&3) + 8*(i>>2) + 4*hi ; q = lane&31
    u16* obase = Ob + ((size_t)(b*2048 + q0 + l31))*1024 + h*64 + hi*4;
    #pragma unroll
    for (int u=0; u<4; ++u){
      ushort4 w0, w1;
      w0.x = f2hbits(o0[4*u+0]*linv); w0.y = f2hbits(o0[4*u+1]*linv);
      w0.z = f2hbits(o0[4*u+2]*linv); w0.w = f2hbits(o0[4*u+3]*linv);
      w1.x = f2hbits(o1[4*u+0]*linv); w1.y = f2hbits(o1[4*u+1]*linv);
      w1.z = f2hbits(o1[4*u+2]*linv); w1.w = f2hbits(o1[4*u+3]*linv);
      *(ushort4*)(obase + u*8)      = w0;
      *(ushort4*)(obase + 32 + u*8) = w1;
    }
  }
}

extern "C" void kernel_launch(void* const* d_in, const int* in_sizes, int n_in,
                              void* d_out, int out_size, void* d_ws, size_t ws_size,
                              hipStream_t stream) {
  const float* x    = (const float*)d_in[0];
  const float* Wq   = (const float*)d_in[1];
  const float* bq   = (const float*)d_in[2];
  const float* Wk   = (const float*)d_in[3];
  const float* bk   = (const float*)d_in[4];
  const float* Wv   = (const float*)d_in[5];
  const float* bv   = (const float*)d_in[6];
  const float* WO_w = (const float*)d_in[7];
  const float* WO_b = (const float*)d_in[8];

  char* ws = (char*)d_ws;
  u16* x16  = (u16*)(ws);
  u16* Wt   = (u16*)(ws + 16777216);
  u16* WO16 = (u16*)(ws + 23068672);
  u16* Qb   = (u16*)(ws + 25165824);
  u16* Kb   = (u16*)(ws + 41943040);
  u16* Vtb  = (u16*)(ws + 58720256);
  u16* Ob   = (u16*)(ws + 75497472);

  f2h_kernel<<<8192, 256, 0, stream>>>(x, x16, 2097152);
  f2h_kernel<<<1024, 256, 0, stream>>>(WO_w, WO16, 262144);
  wtr_kernel<<<dim3(16,16,3), 256, 0, stream>>>(Wq, Wk, Wv, Wt);
  gemm_nt<0><<<dim3(64,8,3), 256, 0, stream>>>(x16, Wt, bq, bk, bv, Qb, Kb, Vtb, nullptr);
  attn_kernel<<<2048, 256, 0, stream>>>(Qb, Kb, Vtb, Ob);
  gemm_nt<1><<<dim3(8,16,4), 256, 0, stream>>>(WO16, Ob, WO_b, nullptr, nullptr,
                                               nullptr, nullptr, nullptr, (float*)d_out);
}

// Round 15
// 202.795 us; speedup vs baseline: 1.0038x; 1.0038x over previous
//
#include <hip/hip_runtime.h>
#include <hip/hip_fp16.h>

typedef unsigned short u16;
typedef __attribute__((ext_vector_type(8))) _Float16 h8;
typedef __attribute__((ext_vector_type(2))) _Float16 h2;
typedef __attribute__((ext_vector_type(2))) __fp16 fp16x2;
typedef __attribute__((ext_vector_type(8))) short s16x8;
typedef __attribute__((ext_vector_type(4))) float fx4;
typedef __attribute__((ext_vector_type(16))) float f32x16;
typedef __attribute__((ext_vector_type(2))) unsigned int u32x2;

#define MFMA16(a,b,c) __builtin_amdgcn_mfma_f32_16x16x32_f16((a),(b),(c),0,0,0)
#define MFMA32(a,b,c) __builtin_amdgcn_mfma_f32_32x32x16_f16((a),(b),(c),0,0,0)

#if __has_builtin(__builtin_amdgcn_exp2f)
#define EXP2(x) __builtin_amdgcn_exp2f(x)
#else
#define EXP2(x) exp2f(x)
#endif

#if __has_builtin(__builtin_amdgcn_global_load_lds)
#define HAS_GLL 1
// async global->LDS, 16B per lane. LDS dest = wave-uniform base + lane*16 (HW).
static __device__ __forceinline__ void gll16(const u16* g, const u16* l){
  __builtin_amdgcn_global_load_lds(
      (const __attribute__((address_space(1))) void*)g,
      (__attribute__((address_space(3))) void*)(uint32_t)(uintptr_t)(const void*)l,
      16, 0, 0);
}
#else
#define HAS_GLL 0
#endif

static __device__ __forceinline__ u16 f2hbits(float x){
  __half h = __float2half_rn(x);
  union { __half h; u16 u; } c; c.h = h; return c.u;
}
static __device__ __forceinline__ uint32_t pkh(float a, float b){
#if __has_builtin(__builtin_amdgcn_cvt_pkrtz)
  union { fp16x2 h; uint32_t u; } c;
  c.h = __builtin_amdgcn_cvt_pkrtz(a, b);
  return c.u;
#else
  __half2 h = __floats2half2_rn(a, b);
  union { __half2 h; uint32_t u; } c; c.h = h; return c.u;
#endif
}
// l += pk.lo + pk.hi  via v_dot2_f32_f16 (sums the exact fp16 P used by PV)
static __device__ __forceinline__ float dot2h(uint32_t u, float c){
  union { uint32_t x; h2 h; } cv; cv.x = u;
  h2 one; one[0] = (_Float16)1.0f; one[1] = (_Float16)1.0f;
  return __builtin_amdgcn_fdot2(cv.h, one, c, false);
}

// ---------------- prep: fp32 -> fp16 cast ----------------
__global__ void f2h_kernel(const float* __restrict__ in, u16* __restrict__ out, int n4){
  int i = blockIdx.x*256 + threadIdx.x;
  if (i < n4){
    float4 v = ((const float4*)in)[i];
    ushort4 o;
    o.x = f2hbits(v.x); o.y = f2hbits(v.y); o.z = f2hbits(v.z); o.w = f2hbits(v.w);
    ((ushort4*)out)[i] = o;
  }
}

// ---------------- prep: W[h][n][d] -> Wt[h*64+d][n] fp16 ----------------
__global__ void wtr_kernel(const float* __restrict__ Wq, const float* __restrict__ Wk,
                           const float* __restrict__ Wv, u16* __restrict__ Wt){
  __shared__ float tl[64][65];
  int z = blockIdx.z, h = blockIdx.y, n0 = blockIdx.x*64;
  const float* W = (z==0)?Wq:((z==1)?Wk:Wv);
  W += (size_t)h*65536;  // h * 1024 * 64
  int t = threadIdx.x;
  #pragma unroll
  for (int i=0;i<16;++i){
    int idx = t + i*256; int r = idx>>6, c = idx&63;
    tl[r][c] = W[(size_t)(n0+r)*64 + c];
  }
  __syncthreads();
  u16* O = Wt + (size_t)z*1048576 + (size_t)h*64*1024 + n0;
  #pragma unroll
  for (int i=0;i<16;++i){
    int idx = t + i*256; int r2 = idx>>6, c2 = idx&63;
    O[(size_t)r2*1024 + c2] = f2hbits(tl[c2][r2]);
  }
}

// ---------------- 128x128x(K=1024) NT GEMM, fp16 MFMA ----------------
// Staging via global_load_lds width=16 (async direct-to-LDS, m97 schedule).
// EPI==0 epilogue writes Q/K/V in MFMA-FRAGMENT-PACKED layout; Q pre-scaled
// by 0.125*log2(e) (attention softmax runs in log2 domain).
template<int EPI>
__launch_bounds__(256, 2)
__global__ void gemm_nt(const u16* __restrict__ A, const u16* __restrict__ Bbase,
                        const float* __restrict__ bias0, const float* __restrict__ bias1,
                        const float* __restrict__ bias2,
                        u16* __restrict__ out0, u16* __restrict__ out1, u16* __restrict__ out2,
                        float* __restrict__ fout){
  __shared__ __align__(16) u16 lds[16384];
  const int K = 1024;
  int mt = blockIdx.x, ntile = blockIdx.y, z = blockIdx.z;
  int m0 = mt*128, n0 = ntile*128;
  const u16* Ap = A;
  const u16* Bp = (EPI==0) ? (Bbase + (size_t)z*1048576) : (Bbase + (size_t)z*2097152);
  int t = threadIdx.x;
  int lane = t & 63, wv = t>>6, g = lane>>4, q15 = lane&15;
  int wr = wv>>1, wc = wv&1;

  fx4 zero4 = {0.f,0.f,0.f,0.f};
  fx4 acc[4][4];
  #pragma unroll
  for (int i=0;i<4;++i)
    #pragma unroll
    for (int j=0;j<4;++j) acc[i][j] = zero4;

  int rowA = t>>2, col8 = (t&3)*8;
  const u16* gA0 = Ap + (size_t)(m0+rowA)*K + col8;
  const u16* gA1 = Ap + (size_t)(m0+rowA+64)*K + col8;
  const u16* gB0 = Bp + (size_t)(n0+rowA)*K + col8;
  const u16* gB1 = Bp + (size_t)(n0+rowA+64)*K + col8;
  int cur = 0;

#if HAS_GLL
  u16* st = lds + wv*512;         // wave-uniform region base (HW adds lane*16B)
  {
    gll16(gA0, st);
    gll16(gA1, st + 2048);
    gll16(gB0, st + 4096);
    gll16(gB1, st + 6144);
  }
  for (int kt=0; kt<32; ++kt){
    __syncthreads();              // drains vmcnt: buf[cur] ready
    if (kt+1 < 32){
      int k0 = (kt+1)*32;
      u16* nb = st + (cur^1)*8192;
      gll16(gA0 + k0, nb);
      gll16(gA1 + k0, nb + 2048);
      gll16(gB0 + k0, nb + 4096);
      gll16(gB1 + k0, nb + 6144);
    }
    const u16* bufA = lds + cur*8192;
    const u16* bufB = bufA + 4096;
    h8 af[4], bf[4];
    #pragma unroll
    for (int f=0; f<4; ++f)
      af[f] = *(const h8*)(bufA + (wr*64 + f*16 + q15)*32 + g*8);
    #pragma unroll
    for (int f=0; f<4; ++f)
      bf[f] = *(const h8*)(bufB + (wc*64 + f*16 + q15)*32 + g*8);
    #pragma unroll
    for (int i=0;i<4;++i)
      #pragma unroll
      for (int j=0;j<4;++j)
        acc[i][j] = MFMA16(af[i], bf[j], acc[i][j]);
    cur ^= 1;
  }
#else
  s16x8 sa0 = *(const s16x8*)(gA0);
  s16x8 sa1 = *(const s16x8*)(gA1);
  s16x8 sb0 = *(const s16x8*)(gB0);
  s16x8 sb1 = *(const s16x8*)(gB1);
  *(s16x8*)(lds + t*8)        = sa0;
  *(s16x8*)(lds + 2048 + t*8) = sa1;
  *(s16x8*)(lds + 4096 + t*8) = sb0;
  *(s16x8*)(lds + 6144 + t*8) = sb1;
  for (int kt=0; kt<32; ++kt){
    if (kt+1 < 32){
      int k0 = (kt+1)*32;
      sa0 = *(const s16x8*)(gA0 + k0);
      sa1 = *(const s16x8*)(gA1 + k0);
      sb0 = *(const s16x8*)(gB0 + k0);
      sb1 = *(const s16x8*)(gB1 + k0);
    }
    __syncthreads();
    const u16* bufA = lds + cur*8192;
    const u16* bufB = bufA + 4096;
    h8 af[4], bf[4];
    #pragma unroll
    for (int f=0; f<4; ++f)
      af[f] = *(const h8*)(bufA + (wr*64 + f*16 + q15)*32 + g*8);
    #pragma unroll
    for (int f=0; f<4; ++f)
      bf[f] = *(const h8*)(bufB + (wc*64 + f*16 + q15)*32 + g*8);
    #pragma unroll
    for (int i=0;i<4;++i)
      #pragma unroll
      for (int j=0;j<4;++j)
        acc[i][j] = MFMA16(af[i], bf[j], acc[i][j]);
    if (kt+1 < 32){
      u16* nb = lds + (cur^1)*8192;
      *(s16x8*)(nb + t*8)        = sa0;
      *(s16x8*)(nb + 2048 + t*8) = sa1;
      *(s16x8*)(nb + 4096 + t*8) = sb0;
      *(s16x8*)(nb + 6144 + t*8) = sb1;
      cur ^= 1;
    }
  }
#endif

  if constexpr (EPI==0){
    const float* bias = (z==0)?bias0:((z==1)?bias1:bias2);
    float bcol[4];
    #pragma unroll
    for (int fj=0;fj<4;++fj) bcol[fj] = bias[n0 + wc*64 + fj*16 + q15];
    int bb = m0 >> 11;            // batch (tiles never cross batch)
    int s_base = (m0 & 2047) + wr*64;
    if (z < 2){
      u16* o = (z==0)? out0 : out1;
      float sc = (z==0)? 0.180336880f : 1.0f;   // Q: 0.125 * log2(e)
      #pragma unroll
      for (int fi=0;fi<4;++fi)
        #pragma unroll
        for (int fj=0;fj<4;++fj){
          int n = n0 + wc*64 + fj*16 + q15;
          int hh = n>>6, d = n&63;
          int sf = d>>4, h2i = (d>>3)&1, j = d&7;
          size_t base = ((size_t)(bb*16+hh)<<17);
          #pragma unroll
          for (int r=0;r<4;++r){
            int s = s_base + fi*16 + g*4 + r;
            int kt2 = s>>5, l = s&31;
            float v = (acc[fi][fj][r] + bcol[fj]) * sc;
            o[base + (((size_t)((kt2*8 + sf*2 + h2i)*32 + l))<<3) + j] = f2hbits(v);
          }
        }
    } else {
      // V fragment-packed
      #pragma unroll
      for (int fi=0;fi<4;++fi)
        #pragma unroll
        for (int fj=0;fj<4;++fj){
          int n = n0 + wc*64 + fj*16 + q15;
          int hh = n>>6, d = n&63;
          size_t base = ((size_t)(bb*16+hh)<<17);
          int kt2 = (s_base + fi*16)>>5;
          int tt = fi & 1;
          int h2v = g>>1;
          int jv = (g&1)*4;
          ushort4 pk;
          pk.x = f2hbits(acc[fi][fj][0] + bcol[fj]);
          pk.y = f2hbits(acc[fi][fj][1] + bcol[fj]);
          pk.z = f2hbits(acc[fi][fj][2] + bcol[fj]);
          pk.w = f2hbits(acc[fi][fj][3] + bcol[fj]);
          *(ushort4*)(out2 + base + (((size_t)((kt2*4 + tt*2 + h2v)*64 + d))<<3) + jv) = pk;
        }
    }
  } else {
    int bb = z;
    float brow[4][4];
    #pragma unroll
    for (int fi=0;fi<4;++fi)
      #pragma unroll
      for (int r=0;r<4;++r) brow[fi][r] = bias0[m0 + wr*64 + fi*16 + g*4 + r];
    #pragma unroll
    for (int fi=0;fi<4;++fi)
      #pragma unroll
      for (int fj=0;fj<4;++fj){
        int scol = n0 + wc*64 + fj*16 + q15;
        #pragma unroll
        for (int r=0;r<4;++r){
          int orow = m0 + wr*64 + fi*16 + g*4 + r;
          fout[((size_t)bb<<21) + ((size_t)orow<<11) + scol] = acc[fi][fj][r] + brow[fi][r];
        }
      }
  }
}

// ---------------- flash attention, 32x32 swapped, split-KV + wave desync -----
// Round-13 structure (512-thr, 8 waves = 4 q-pairs x 2 KV-halves, linear
// combine) + TWO desync changes:
//  (a) temporal stagger: wave wv sleeps ~128cy x wv before the sweep, so the
//      8 lockstep instruction streams phase-shift across one tile period --
//      some waves MFMA while others run exp/pack VALU (fills the MFMA pipe).
//  (b) address rotation: wave starts its 32-tile sweep at tile wv*4 (mod 32;
//      fixed-max softmax is order-independent) so staggered waves also touch
//      different L2 lines at any instant.
__launch_bounds__(512)
__global__ void attn_kernel(const u16* __restrict__ Qb, const u16* __restrict__ Kb,
                            const u16* __restrict__ Vt, u16* __restrict__ Ob){
  __shared__ float sO[4][32][64];   // odd-wave partial O   (32 KB)
  __shared__ float sL[4][64];       // odd-wave partial l   (1 KB)
  int bid = blockIdx.x;
  int g63 = bid & 63, qb = bid >> 6;     // qb in 0..15
  int b = g63 >> 4, h = g63 & 15;
  int t = threadIdx.x;
  int lane = t & 63, wv = t >> 6;        // wv in 0..7
  int pair = wv >> 1, half = wv & 1;
  int l31 = lane&31, hi = lane>>5;
  size_t bh = (size_t)(b*16 + h);
  const u16* Qp = Qb + (bh<<17);   // fragment-packed
  const u16* Kp = Kb + (bh<<17);
  const u16* Vp = Vt + (bh<<17);
  int q0 = qb*128 + pair*32;
  int qt = qb*4 + pair;            // q0>>5
  const float NML2E = -5.77078016f;   // -4*log2(e): fixed-max shift (log2 units)

  // Q fragments (B-operand): col=q=lane&31, k = s*16 + hi*8 + j
  h8 qf[4];
  #pragma unroll
  for (int s=0;s<4;++s)
    qf[s] = *(const h8*)(Qp + (((size_t)((qt*8 + s*2 + hi)*32 + l31))<<3));

  f32x16 o0, o1, sinit;
  #pragma unroll
  for (int i=0;i<16;++i){ o0[i]=0.f; o1[i]=0.f; sinit[i]=NML2E; }
  float l_run = 0.f;

  // this wave's KV half: 32 tiles at base half*32 (tile stride 2048 u16)
  const u16* kb0 = Kp + half*65536 + (hi*256 + l31*8);
  const u16* vb0 = Vp + half*65536 + (hi*512 + l31*8);
  int start = wv*4;   // per-wave rotation within the 32-tile sweep

  auto LOADKV = [&](const u16* kp, const u16* vp, h8 (&kf_)[4], h8 (&vf_)[4]) {
    kf_[0] = *(const h8*)(kp);
    kf_[1] = *(const h8*)(kp + 512);
    kf_[2] = *(const h8*)(kp + 1024);
    kf_[3] = *(const h8*)(kp + 1536);
    vf_[0] = *(const h8*)(vp);
    vf_[1] = *(const h8*)(vp + 256);
    vf_[2] = *(const h8*)(vp + 1024);
    vf_[3] = *(const h8*)(vp + 1280);
  };

  auto TILE = [&](h8 (&kf_)[4], h8 (&vf_)[4]) {
    __builtin_amdgcn_s_setprio(1);
    f32x16 S = MFMA32(kf_[0], qf[0], sinit);   // C-operand carries the shift
    S = MFMA32(kf_[1], qf[1], S);
    S = MFMA32(kf_[2], qf[2], S);
    S = MFMA32(kf_[3], qf[3], S);
    __builtin_amdgcn_s_setprio(0);
    // S[i]: kv = (i&3) + 8*(i>>2) + 4*hi (local), q = lane&31, log2 units

    float p[16];
    #pragma unroll
    for (int i=0;i<16;++i) p[i] = EXP2(S[i]);

    #pragma unroll
    for (int tt=0; tt<2; ++tt){
      uint32_t A0 = pkh(p[8*tt+0], p[8*tt+1]);
      uint32_t A1 = pkh(p[8*tt+2], p[8*tt+3]);
      uint32_t B0 = pkh(p[8*tt+4], p[8*tt+5]);
      uint32_t B1 = pkh(p[8*tt+6], p[8*tt+7]);
      l_run = dot2h(A0, dot2h(A1, dot2h(B0, dot2h(B1, l_run))));
      union { uint32_t u[4]; h8 v; } pf;
#if __has_builtin(__builtin_amdgcn_permlane32_swap)
      u32x2 rx = __builtin_amdgcn_permlane32_swap(A0, B0, false, false);
      u32x2 ry = __builtin_amdgcn_permlane32_swap(A1, B1, false, false);
      pf.u[0] = rx[0]; pf.u[1] = ry[0]; pf.u[2] = rx[1]; pf.u[3] = ry[1];
#else
      uint32_t s0 = hi ? A0 : B0, s1 = hi ? A1 : B1;
      uint32_t r0 = __shfl_xor(s0, 32), r1 = __shfl_xor(s1, 32);
      pf.u[0] = hi ? r0 : A0;
      pf.u[1] = hi ? r1 : A1;
      pf.u[2] = hi ? B0 : r0;
      pf.u[3] = hi ? B1 : r1;
#endif
      __builtin_amdgcn_s_setprio(1);
      if (tt == 0){
        o0 = MFMA32(vf_[0], pf.v, o0);
        o1 = MFMA32(vf_[1], pf.v, o1);
      } else {
        o0 = MFMA32(vf_[2], pf.v, o0);
        o1 = MFMA32(vf_[3], pf.v, o1);
      }
      __builtin_amdgcn_s_setprio(0);
    }
  };

  // temporal stagger: ~128cy per wave index (wave-uniform scalar loop)
#if __has_builtin(__builtin_amdgcn_s_sleep)
  for (int i=0;i<wv;++i) __builtin_amdgcn_s_sleep(2);
#endif

  h8 kfA[4], vfA[4], kfB[4], vfB[4];
  LOADKV(kb0 + start*2048, vb0 + start*2048, kfA, vfA);
  for (int kt=0; kt<32; kt+=2){
    int tB = (start + kt + 1) & 31;
    LOADKV(kb0 + tB*2048, vb0 + tB*2048, kfB, vfB);
    TILE(kfA, vfA);
    if (kt+2 < 32){
      int tA = (start + kt + 2) & 31;
      LOADKV(kb0 + tA*2048, vb0 + tA*2048, kfA, vfA);
    }
    TILE(kfB, vfB);
  }

  // ---- split-KV combine: odd wave -> LDS; even wave adds, normalizes, stores
  if (half){
    #pragma unroll
    for (int i=0;i<16;++i){
      sO[pair][i][lane]    = o0[i];
      sO[pair][16+i][lane] = o1[i];
    }
    sL[pair][lane] = l_run;
  }
  __syncthreads();
  if (!half){
    #pragma unroll
    for (int i=0;i<16;++i){
      o0[i] += sO[pair][i][lane];
      o1[i] += sO[pair][16+i][lane];
    }
    l_run += sL[pair][lane];
    // cross-half l combine (lane hi halves own disjoint kv), once
    float l_tot = l_run + __shfl_xor(l_run, 32);
    float linv = 1.f / l_tot;
    // o{0,1}[i]: d = 32*dt + (i&3) + 8*(i>>2) + 4*hi ; q = lane&31
    u16* obase = Ob + ((size_t)(b*2048 + q0 + l31))*1024 + h*64 + hi*4;
    #pragma unroll
    for (int u=0; u<4; ++u){
      ushort4 w0, w1;
      w0.x = f2hbits(o0[4*u+0]*linv); w0.y = f2hbits(o0[4*u+1]*linv);
      w0.z = f2hbits(o0[4*u+2]*linv); w0.w = f2hbits(o0[4*u+3]*linv);
      w1.x = f2hbits(o1[4*u+0]*linv); w1.y = f2hbits(o1[4*u+1]*linv);
      w1.z = f2hbits(o1[4*u+2]*linv); w1.w = f2hbits(o1[4*u+3]*linv);
      *(ushort4*)(obase + u*8)      = w0;
      *(ushort4*)(obase + 32 + u*8) = w1;
    }
  }
}

extern "C" void kernel_launch(void* const* d_in, const int* in_sizes, int n_in,
                              void* d_out, int out_size, void* d_ws, size_t ws_size,
                              hipStream_t stream) {
  const float* x    = (const float*)d_in[0];
  const float* Wq   = (const float*)d_in[1];
  const float* bq   = (const float*)d_in[2];
  const float* Wk   = (const float*)d_in[3];
  const float* bk   = (const float*)d_in[4];
  const float* Wv   = (const float*)d_in[5];
  const float* bv   = (const float*)d_in[6];
  const float* WO_w = (const float*)d_in[7];
  const float* WO_b = (const float*)d_in[8];

  char* ws = (char*)d_ws;
  u16* x16  = (u16*)(ws);
  u16* Wt   = (u16*)(ws + 16777216);
  u16* WO16 = (u16*)(ws + 23068672);
  u16* Qb   = (u16*)(ws + 25165824);
  u16* Kb   = (u16*)(ws + 41943040);
  u16* Vtb  = (u16*)(ws + 58720256);
  u16* Ob   = (u16*)(ws + 75497472);

  f2h_kernel<<<8192, 256, 0, stream>>>(x, x16, 2097152);
  f2h_kernel<<<1024, 256, 0, stream>>>(WO_w, WO16, 262144);
  wtr_kernel<<<dim3(16,16,3), 256, 0, stream>>>(Wq, Wk, Wv, Wt);
  gemm_nt<0><<<dim3(64,8,3), 256, 0, stream>>>(x16, Wt, bq, bk, bv, Qb, Kb, Vtb, nullptr);
  attn_kernel<<<1024, 512, 0, stream>>>(Qb, Kb, Vtb, Ob);
  gemm_nt<1><<<dim3(8,16,4), 256, 0, stream>>>(WO16, Ob, WO_b, nullptr, nullptr,
                                               nullptr, nullptr, nullptr, (float*)d_out);
}

// Round 17
// 197.116 us; speedup vs baseline: 1.0327x; 1.0288x over previous
//
#include <hip/hip_runtime.h>
#include <hip/hip_fp16.h>

typedef unsigned short u16;
typedef __attribute__((ext_vector_type(8))) _Float16 h8;
typedef __attribute__((ext_vector_type(2))) _Float16 h2;
typedef __attribute__((ext_vector_type(2))) __fp16 fp16x2;
typedef __attribute__((ext_vector_type(8))) short s16x8;
typedef __attribute__((ext_vector_type(4))) float fx4;
typedef __attribute__((ext_vector_type(16))) float f32x16;
typedef __attribute__((ext_vector_type(2))) unsigned int u32x2;

#define MFMA16(a,b,c) __builtin_amdgcn_mfma_f32_16x16x32_f16((a),(b),(c),0,0,0)
#define MFMA32(a,b,c) __builtin_amdgcn_mfma_f32_32x32x16_f16((a),(b),(c),0,0,0)

#if __has_builtin(__builtin_amdgcn_exp2f)
#define EXP2(x) __builtin_amdgcn_exp2f(x)
#else
#define EXP2(x) exp2f(x)
#endif

#if __has_builtin(__builtin_amdgcn_global_load_lds)
#define HAS_GLL 1
// async global->LDS, 16B per lane. LDS dest = wave-uniform base + lane*16 (HW).
static __device__ __forceinline__ void gll16(const u16* g, const u16* l){
  __builtin_amdgcn_global_load_lds(
      (const __attribute__((address_space(1))) void*)g,
      (__attribute__((address_space(3))) void*)(uint32_t)(uintptr_t)(const void*)l,
      16, 0, 0);
}
#else
#define HAS_GLL 0
#endif

static __device__ __forceinline__ u16 f2hbits(float x){
  __half h = __float2half_rn(x);
  union { __half h; u16 u; } c; c.h = h; return c.u;
}
static __device__ __forceinline__ uint32_t pkh(float a, float b){
#if __has_builtin(__builtin_amdgcn_cvt_pkrtz)
  union { fp16x2 h; uint32_t u; } c;
  c.h = __builtin_amdgcn_cvt_pkrtz(a, b);
  return c.u;
#else
  __half2 h = __floats2half2_rn(a, b);
  union { __half2 h; uint32_t u; } c; c.h = h; return c.u;
#endif
}
// l += pk.lo + pk.hi  via v_dot2_f32_f16 (sums the exact fp16 P used by PV)
static __device__ __forceinline__ float dot2h(uint32_t u, float c){
  union { uint32_t x; h2 h; } cv; cv.x = u;
  h2 one; one[0] = (_Float16)1.0f; one[1] = (_Float16)1.0f;
  return __builtin_amdgcn_fdot2(cv.h, one, c, false);
}

// ---------------- prep: fp32 -> fp16 cast (x and WO in ONE launch) ----------
__global__ void f2h2_kernel(const float* __restrict__ a, u16* __restrict__ oa, int na4,
                            const float* __restrict__ b, u16* __restrict__ ob, int nb4){
  int i = blockIdx.x*256 + threadIdx.x;
  if (i < na4){
    float4 v = ((const float4*)a)[i];
    ushort4 o;
    o.x = f2hbits(v.x); o.y = f2hbits(v.y); o.z = f2hbits(v.z); o.w = f2hbits(v.w);
    ((ushort4*)oa)[i] = o;
  } else {
    int j = i - na4;
    if (j < nb4){
      float4 v = ((const float4*)b)[j];
      ushort4 o;
      o.x = f2hbits(v.x); o.y = f2hbits(v.y); o.z = f2hbits(v.z); o.w = f2hbits(v.w);
      ((ushort4*)ob)[j] = o;
    }
  }
}

// ---------------- prep: W[h][n][d] -> Wt[h*64+d][n] fp16 ----------------
__global__ void wtr_kernel(const float* __restrict__ Wq, const float* __restrict__ Wk,
                           const float* __restrict__ Wv, u16* __restrict__ Wt){
  __shared__ float tl[64][65];
  int z = blockIdx.z, h = blockIdx.y, n0 = blockIdx.x*64;
  const float* W = (z==0)?Wq:((z==1)?Wk:Wv);
  W += (size_t)h*65536;  // h * 1024 * 64
  int t = threadIdx.x;
  #pragma unroll
  for (int i=0;i<16;++i){
    int idx = t + i*256; int r = idx>>6, c = idx&63;
    tl[r][c] = W[(size_t)(n0+r)*64 + c];
  }
  __syncthreads();
  u16* O = Wt + (size_t)z*1048576 + (size_t)h*64*1024 + n0;
  #pragma unroll
  for (int i=0;i<16;++i){
    int idx = t + i*256; int r2 = idx>>6, c2 = idx&63;
    O[(size_t)r2*1024 + c2] = f2hbits(tl[c2][r2]);
  }
}

// ---------------- 128x128x(K=1024) NT GEMM, fp16 MFMA ----------------
// Staging via global_load_lds width=16 (async direct-to-LDS, m97 schedule).
// EPI==0 epilogue writes Q/K/V in MFMA-FRAGMENT-PACKED layout; Q pre-scaled
// by 0.125*log2(e) (attention softmax runs in log2 domain).
template<int EPI>
__launch_bounds__(256, 2)
__global__ void gemm_nt(const u16* __restrict__ A, const u16* __restrict__ Bbase,
                        const float* __restrict__ bias0, const float* __restrict__ bias1,
                        const float* __restrict__ bias2,
                        u16* __restrict__ out0, u16* __restrict__ out1, u16* __restrict__ out2,
                        float* __restrict__ fout){
  __shared__ __align__(16) u16 lds[16384];
  const int K = 1024;
  int mt = blockIdx.x, ntile = blockIdx.y, z = blockIdx.z;
  int m0 = mt*128, n0 = ntile*128;
  const u16* Ap = A;
  const u16* Bp = (EPI==0) ? (Bbase + (size_t)z*1048576) : (Bbase + (size_t)z*2097152);
  int t = threadIdx.x;
  int lane = t & 63, wv = t>>6, g = lane>>4, q15 = lane&15;
  int wr = wv>>1, wc = wv&1;

  fx4 zero4 = {0.f,0.f,0.f,0.f};
  fx4 acc[4][4];
  #pragma unroll
  for (int i=0;i<4;++i)
    #pragma unroll
    for (int j=0;j<4;++j) acc[i][j] = zero4;

  int rowA = t>>2, col8 = (t&3)*8;
  const u16* gA0 = Ap + (size_t)(m0+rowA)*K + col8;
  const u16* gA1 = Ap + (size_t)(m0+rowA+64)*K + col8;
  const u16* gB0 = Bp + (size_t)(n0+rowA)*K + col8;
  const u16* gB1 = Bp + (size_t)(n0+rowA+64)*K + col8;
  int cur = 0;

#if HAS_GLL
  u16* st = lds + wv*512;         // wave-uniform region base (HW adds lane*16B)
  {
    gll16(gA0, st);
    gll16(gA1, st + 2048);
    gll16(gB0, st + 4096);
    gll16(gB1, st + 6144);
  }
  for (int kt=0; kt<32; ++kt){
    __syncthreads();              // drains vmcnt: buf[cur] ready
    if (kt+1 < 32){
      int k0 = (kt+1)*32;
      u16* nb = st + (cur^1)*8192;
      gll16(gA0 + k0, nb);
      gll16(gA1 + k0, nb + 2048);
      gll16(gB0 + k0, nb + 4096);
      gll16(gB1 + k0, nb + 6144);
    }
    const u16* bufA = lds + cur*8192;
    const u16* bufB = bufA + 4096;
    h8 af[4], bf[4];
    #pragma unroll
    for (int f=0; f<4; ++f)
      af[f] = *(const h8*)(bufA + (wr*64 + f*16 + q15)*32 + g*8);
    #pragma unroll
    for (int f=0; f<4; ++f)
      bf[f] = *(const h8*)(bufB + (wc*64 + f*16 + q15)*32 + g*8);
    #pragma unroll
    for (int i=0;i<4;++i)
      #pragma unroll
      for (int j=0;j<4;++j)
        acc[i][j] = MFMA16(af[i], bf[j], acc[i][j]);
    cur ^= 1;
  }
#else
  s16x8 sa0 = *(const s16x8*)(gA0);
  s16x8 sa1 = *(const s16x8*)(gA1);
  s16x8 sb0 = *(const s16x8*)(gB0);
  s16x8 sb1 = *(const s16x8*)(gB1);
  *(s16x8*)(lds + t*8)        = sa0;
  *(s16x8*)(lds + 2048 + t*8) = sa1;
  *(s16x8*)(lds + 4096 + t*8) = sb0;
  *(s16x8*)(lds + 6144 + t*8) = sb1;
  for (int kt=0; kt<32; ++kt){
    if (kt+1 < 32){
      int k0 = (kt+1)*32;
      sa0 = *(const s16x8*)(gA0 + k0);
      sa1 = *(const s16x8*)(gA1 + k0);
      sb0 = *(const s16x8*)(gB0 + k0);
      sb1 = *(const s16x8*)(gB1 + k0);
    }
    __syncthreads();
    const u16* bufA = lds + cur*8192;
    const u16* bufB = bufA + 4096;
    h8 af[4], bf[4];
    #pragma unroll
    for (int f=0; f<4; ++f)
      af[f] = *(const h8*)(bufA + (wr*64 + f*16 + q15)*32 + g*8);
    #pragma unroll
    for (int f=0; f<4; ++f)
      bf[f] = *(const h8*)(bufB + (wc*64 + f*16 + q15)*32 + g*8);
    #pragma unroll
    for (int i=0;i<4;++i)
      #pragma unroll
      for (int j=0;j<4;++j)
        acc[i][j] = MFMA16(af[i], bf[j], acc[i][j]);
    if (kt+1 < 32){
      u16* nb = lds + (cur^1)*8192;
      *(s16x8*)(nb + t*8)        = sa0;
      *(s16x8*)(nb + 2048 + t*8) = sa1;
      *(s16x8*)(nb + 4096 + t*8) = sb0;
      *(s16x8*)(nb + 6144 + t*8) = sb1;
      cur ^= 1;
    }
  }
#endif

  if constexpr (EPI==0){
    const float* bias = (z==0)?bias0:((z==1)?bias1:bias2);
    float bcol[4];
    #pragma unroll
    for (int fj=0;fj<4;++fj) bcol[fj] = bias[n0 + wc*64 + fj*16 + q15];
    int bb = m0 >> 11;            // batch (tiles never cross batch)
    int s_base = (m0 & 2047) + wr*64;
    if (z < 2){
      u16* o = (z==0)? out0 : out1;
      float sc = (z==0)? 0.180336880f : 1.0f;   // Q: 0.125 * log2(e)
      #pragma unroll
      for (int fi=0;fi<4;++fi)
        #pragma unroll
        for (int fj=0;fj<4;++fj){
          int n = n0 + wc*64 + fj*16 + q15;
          int hh = n>>6, d = n&63;
          int sf = d>>4, h2i = (d>>3)&1, j = d&7;
          size_t base = ((size_t)(bb*16+hh)<<17);
          #pragma unroll
          for (int r=0;r<4;++r){
            int s = s_base + fi*16 + g*4 + r;
            int kt2 = s>>5, l = s&31;
            float v = (acc[fi][fj][r] + bcol[fj]) * sc;
            o[base + (((size_t)((kt2*8 + sf*2 + h2i)*32 + l))<<3) + j] = f2hbits(v);
          }
        }
    } else {
      // V fragment-packed
      #pragma unroll
      for (int fi=0;fi<4;++fi)
        #pragma unroll
        for (int fj=0;fj<4;++fj){
          int n = n0 + wc*64 + fj*16 + q15;
          int hh = n>>6, d = n&63;
          size_t base = ((size_t)(bb*16+hh)<<17);
          int kt2 = (s_base + fi*16)>>5;
          int tt = fi & 1;
          int h2v = g>>1;
          int jv = (g&1)*4;
          ushort4 pk;
          pk.x = f2hbits(acc[fi][fj][0] + bcol[fj]);
          pk.y = f2hbits(acc[fi][fj][1] + bcol[fj]);
          pk.z = f2hbits(acc[fi][fj][2] + bcol[fj]);
          pk.w = f2hbits(acc[fi][fj][3] + bcol[fj]);
          *(ushort4*)(out2 + base + (((size_t)((kt2*4 + tt*2 + h2v)*64 + d))<<3) + jv) = pk;
        }
    }
  } else {
    int bb = z;
    float brow[4][4];
    #pragma unroll
    for (int fi=0;fi<4;++fi)
      #pragma unroll
      for (int r=0;r<4;++r) brow[fi][r] = bias0[m0 + wr*64 + fi*16 + g*4 + r];
    #pragma unroll
    for (int fi=0;fi<4;++fi)
      #pragma unroll
      for (int fj=0;fj<4;++fj){
        int scol = n0 + wc*64 + fj*16 + q15;
        #pragma unroll
        for (int r=0;r<4;++r){
          int orow = m0 + wr*64 + fi*16 + g*4 + r;
          fout[((size_t)bb<<21) + ((size_t)orow<<11) + scol] = acc[fi][fj][r] + brow[fi][r];
        }
      }
  }
}

// ---------------- flash attention, 32x32 swapped, split-KV in-block ----------
// (round-13 best configuration, verbatim)
// 512-thr blocks: 8 waves = 4 q-tile pairs. Waves (2p, 2p+1) share q-rows
// [qb*128+p*32, +32); wave half=wv&1 sweeps KV tiles [half*32, half*32+32).
// Fixed-max softmax => partials combine LINEARLY: O=Oa+Ob, l=la+lb -- one
// 32KB LDS exchange + one __syncthreads at block end, no rescale.
__launch_bounds__(512)
__global__ void attn_kernel(const u16* __restrict__ Qb, const u16* __restrict__ Kb,
                            const u16* __restrict__ Vt, u16* __restrict__ Ob){
  __shared__ float sO[4][32][64];   // odd-wave partial O   (32 KB)
  __shared__ float sL[4][64];       // odd-wave partial l   (1 KB)
  int bid = blockIdx.x;
  int g63 = bid & 63, qb = bid >> 6;     // qb in 0..15
  int b = g63 >> 4, h = g63 & 15;
  int t = threadIdx.x;
  int lane = t & 63, wv = t >> 6;        // wv in 0..7
  int pair = wv >> 1, half = wv & 1;
  int l31 = lane&31, hi = lane>>5;
  size_t bh = (size_t)(b*16 + h);
  const u16* Qp = Qb + (bh<<17);   // fragment-packed
  const u16* Kp = Kb + (bh<<17);
  const u16* Vp = Vt + (bh<<17);
  int q0 = qb*128 + pair*32;
  int qt = qb*4 + pair;            // q0>>5
  const float NML2E = -5.77078016f;   // -4*log2(e): fixed-max shift (log2 units)

  // Q fragments (B-operand): col=q=lane&31, k = s*16 + hi*8 + j
  h8 qf[4];
  #pragma unroll
  for (int s=0;s<4;++s)
    qf[s] = *(const h8*)(Qp + (((size_t)((qt*8 + s*2 + hi)*32 + l31))<<3));

  f32x16 o0, o1, sinit;
  #pragma unroll
  for (int i=0;i<16;++i){ o0[i]=0.f; o1[i]=0.f; sinit[i]=NML2E; }
  float l_run = 0.f;

  // this wave's KV half: 32 tiles, starting at tile half*32 (65536 u16 offset)
  const u16* kc = Kp + half*65536 + (hi*256 + l31*8);
  const u16* vc = Vp + half*65536 + (hi*512 + l31*8);

  auto LOADKV = [&](const u16* kp, const u16* vp, h8 (&kf_)[4], h8 (&vf_)[4]) {
    kf_[0] = *(const h8*)(kp);
    kf_[1] = *(const h8*)(kp + 512);
    kf_[2] = *(const h8*)(kp + 1024);
    kf_[3] = *(const h8*)(kp + 1536);
    vf_[0] = *(const h8*)(vp);
    vf_[1] = *(const h8*)(vp + 256);
    vf_[2] = *(const h8*)(vp + 1024);
    vf_[3] = *(const h8*)(vp + 1280);
  };

  auto TILE = [&](h8 (&kf_)[4], h8 (&vf_)[4]) {
    __builtin_amdgcn_s_setprio(1);
    f32x16 S = MFMA32(kf_[0], qf[0], sinit);   // C-operand carries the shift
    S = MFMA32(kf_[1], qf[1], S);
    S = MFMA32(kf_[2], qf[2], S);
    S = MFMA32(kf_[3], qf[3], S);
    __builtin_amdgcn_s_setprio(0);
    // S[i]: kv = (i&3) + 8*(i>>2) + 4*hi (local), q = lane&31, log2 units

    float p[16];
    #pragma unroll
    for (int i=0;i<16;++i) p[i] = EXP2(S[i]);

    #pragma unroll
    for (int tt=0; tt<2; ++tt){
      uint32_t A0 = pkh(p[8*tt+0], p[8*tt+1]);
      uint32_t A1 = pkh(p[8*tt+2], p[8*tt+3]);
      uint32_t B0 = pkh(p[8*tt+4], p[8*tt+5]);
      uint32_t B1 = pkh(p[8*tt+6], p[8*tt+7]);
      l_run = dot2h(A0, dot2h(A1, dot2h(B0, dot2h(B1, l_run))));
      union { uint32_t u[4]; h8 v; } pf;
#if __has_builtin(__builtin_amdgcn_permlane32_swap)
      u32x2 rx = __builtin_amdgcn_permlane32_swap(A0, B0, false, false);
      u32x2 ry = __builtin_amdgcn_permlane32_swap(A1, B1, false, false);
      pf.u[0] = rx[0]; pf.u[1] = ry[0]; pf.u[2] = rx[1]; pf.u[3] = ry[1];
#else
      uint32_t s0 = hi ? A0 : B0, s1 = hi ? A1 : B1;
      uint32_t r0 = __shfl_xor(s0, 32), r1 = __shfl_xor(s1, 32);
      pf.u[0] = hi ? r0 : A0;
      pf.u[1] = hi ? r1 : A1;
      pf.u[2] = hi ? B0 : r0;
      pf.u[3] = hi ? B1 : r1;
#endif
      __builtin_amdgcn_s_setprio(1);
      if (tt == 0){
        o0 = MFMA32(vf_[0], pf.v, o0);
        o1 = MFMA32(vf_[1], pf.v, o1);
      } else {
        o0 = MFMA32(vf_[2], pf.v, o0);
        o1 = MFMA32(vf_[3], pf.v, o1);
      }
      __builtin_amdgcn_s_setprio(0);
    }
  };

  h8 kfA[4], vfA[4], kfB[4], vfB[4];
  LOADKV(kc, vc, kfA, vfA);
  for (int kt=0; kt<32; kt+=2){
    LOADKV(kc+2048, vc+2048, kfB, vfB);
    TILE(kfA, vfA);
    if (kt+2 < 32) LOADKV(kc+4096, vc+4096, kfA, vfA);
    kc += 4096; vc += 4096;
    TILE(kfB, vfB);
  }

  // ---- split-KV combine: odd wave -> LDS; even wave adds, normalizes, stores
  if (half){
    #pragma unroll
    for (int i=0;i<16;++i){
      sO[pair][i][lane]    = o0[i];
      sO[pair][16+i][lane] = o1[i];
    }
    sL[pair][lane] = l_run;
  }
  __syncthreads();
  if (!half){
    #pragma unroll
    for (int i=0;i<16;++i){
      o0[i] += sO[pair][i][lane];
      o1[i] += sO[pair][16+i][lane];
    }
    l_run += sL[pair][lane];
    // cross-half l combine (lane hi halves own disjoint kv), once
    float l_tot = l_run + __shfl_xor(l_run, 32);
    float linv = 1.f / l_tot;
    // o{0,1}[i]: d = 32*dt + (i&3) + 8*(i>>2) + 4*hi ; q = lane&31
    u16* obase = Ob + ((size_t)(b*2048 + q0 + l31))*1024 + h*64 + hi*4;
    #pragma unroll
    for (int u=0; u<4; ++u){
      ushort4 w0, w1;
      w0.x = f2hbits(o0[4*u+0]*linv); w0.y = f2hbits(o0[4*u+1]*linv);
      w0.z = f2hbits(o0[4*u+2]*linv); w0.w = f2hbits(o0[4*u+3]*linv);
      w1.x = f2hbits(o1[4*u+0]*linv); w1.y = f2hbits(o1[4*u+1]*linv);
      w1.z = f2hbits(o1[4*u+2]*linv); w1.w = f2hbits(o1[4*u+3]*linv);
      *(ushort4*)(obase + u*8)      = w0;
      *(ushort4*)(obase + 32 + u*8) = w1;
    }
  }
}

extern "C" void kernel_launch(void* const* d_in, const int* in_sizes, int n_in,
                              void* d_out, int out_size, void* d_ws, size_t ws_size,
                              hipStream_t stream) {
  const float* x    = (const float*)d_in[0];
  const float* Wq   = (const float*)d_in[1];
  const float* bq   = (const float*)d_in[2];
  const float* Wk   = (const float*)d_in[3];
  const float* bk   = (const float*)d_in[4];
  const float* Wv   = (const float*)d_in[5];
  const float* bv   = (const float*)d_in[6];
  const float* WO_w = (const float*)d_in[7];
  const float* WO_b = (const float*)d_in[8];

  char* ws = (char*)d_ws;
  u16* x16  = (u16*)(ws);
  u16* Wt   = (u16*)(ws + 16777216);
  u16* WO16 = (u16*)(ws + 23068672);
  u16* Qb   = (u16*)(ws + 25165824);
  u16* Kb   = (u16*)(ws + 41943040);
  u16* Vtb  = (u16*)(ws + 58720256);
  u16* Ob   = (u16*)(ws + 75497472);

  f2h2_kernel<<<9216, 256, 0, stream>>>(x, x16, 2097152, WO_w, WO16, 262144);
  wtr_kernel<<<dim3(16,16,3), 256, 0, stream>>>(Wq, Wk, Wv, Wt);
  gemm_nt<0><<<dim3(64,8,3), 256, 0, stream>>>(x16, Wt, bq, bk, bv, Qb, Kb, Vtb, nullptr);
  attn_kernel<<<1024, 512, 0, stream>>>(Qb, Kb, Vtb, Ob);
  gemm_nt<1><<<dim3(8,16,4), 256, 0, stream>>>(WO16, Ob, WO_b, nullptr, nullptr,
                                               nullptr, nullptr, nullptr, (float*)d_out);
}

// Round 18
// 196.503 us; speedup vs baseline: 1.0360x; 1.0031x over previous
//
#include <hip/hip_runtime.h>
#include <hip/hip_fp16.h>

typedef unsigned short u16;
typedef __attribute__((ext_vector_type(8))) _Float16 h8;
typedef __attribute__((ext_vector_type(2))) _Float16 h2;
typedef __attribute__((ext_vector_type(2))) __fp16 fp16x2;
typedef __attribute__((ext_vector_type(8))) short s16x8;
typedef __attribute__((ext_vector_type(4))) float fx4;
typedef __attribute__((ext_vector_type(16))) float f32x16;
typedef __attribute__((ext_vector_type(2))) unsigned int u32x2;

#define MFMA16(a,b,c) __builtin_amdgcn_mfma_f32_16x16x32_f16((a),(b),(c),0,0,0)
#define MFMA32(a,b,c) __builtin_amdgcn_mfma_f32_32x32x16_f16((a),(b),(c),0,0,0)

#if __has_builtin(__builtin_amdgcn_exp2f)
#define EXP2(x) __builtin_amdgcn_exp2f(x)
#else
#define EXP2(x) exp2f(x)
#endif

#if __has_builtin(__builtin_amdgcn_global_load_lds)
#define HAS_GLL 1
// async global->LDS, 16B per lane. LDS dest = wave-uniform base + lane*16 (HW).
static __device__ __forceinline__ void gll16(const u16* g, const u16* l){
  __builtin_amdgcn_global_load_lds(
      (const __attribute__((address_space(1))) void*)g,
      (__attribute__((address_space(3))) void*)(uint32_t)(uintptr_t)(const void*)l,
      16, 0, 0);
}
#else
#define HAS_GLL 0
#endif

static __device__ __forceinline__ u16 f2hbits(float x){
  __half h = __float2half_rn(x);
  union { __half h; u16 u; } c; c.h = h; return c.u;
}
static __device__ __forceinline__ uint32_t pkh(float a, float b){
#if __has_builtin(__builtin_amdgcn_cvt_pkrtz)
  union { fp16x2 h; uint32_t u; } c;
  c.h = __builtin_amdgcn_cvt_pkrtz(a, b);
  return c.u;
#else
  __half2 h = __floats2half2_rn(a, b);
  union { __half2 h; uint32_t u; } c; c.h = h; return c.u;
#endif
}
// l += pk.lo + pk.hi  via v_dot2_f32_f16 (sums the exact fp16 P used by PV)
static __device__ __forceinline__ float dot2h(uint32_t u, float c){
  union { uint32_t x; h2 h; } cv; cv.x = u;
  h2 one; one[0] = (_Float16)1.0f; one[1] = (_Float16)1.0f;
  return __builtin_amdgcn_fdot2(cv.h, one, c, false);
}

// ---------------- prep: fp32->fp16 casts (x, WO) + W transpose, ONE launch ---
// blocks [0, 9216): cast x (2097152 float4) then WO (262144 float4)
// blocks [9216, 9984): Wq/Wk/Wv [h][n][d] -> Wt[z][h*64+d][n] fp16
__global__ void prep_kernel(const float* __restrict__ x, u16* __restrict__ x16,
                            const float* __restrict__ WO, u16* __restrict__ WO16,
                            const float* __restrict__ Wq, const float* __restrict__ Wk,
                            const float* __restrict__ Wv, u16* __restrict__ Wt){
  __shared__ float tl[64][65];
  int bid = blockIdx.x;
  int t = threadIdx.x;
  if (bid < 9216){
    int i = bid*256 + t;
    if (i < 2097152){
      float4 v = ((const float4*)x)[i];
      ushort4 o;
      o.x = f2hbits(v.x); o.y = f2hbits(v.y); o.z = f2hbits(v.z); o.w = f2hbits(v.w);
      ((ushort4*)x16)[i] = o;
    } else {
      int j = i - 2097152;
      if (j < 262144){
        float4 v = ((const float4*)WO)[j];
        ushort4 o;
        o.x = f2hbits(v.x); o.y = f2hbits(v.y); o.z = f2hbits(v.z); o.w = f2hbits(v.w);
        ((ushort4*)WO16)[j] = o;
      }
    }
  } else {
    int b2 = bid - 9216;                    // 0..767
    int z = b2 >> 8, rem = b2 & 255;
    int h = rem >> 4, n0 = (rem & 15)*64;
    const float* W = (z==0)?Wq:((z==1)?Wk:Wv);
    W += (size_t)h*65536;                   // h * 1024 * 64
    #pragma unroll
    for (int i=0;i<16;++i){
      int idx = t + i*256; int r = idx>>6, c = idx&63;
      tl[r][c] = W[(size_t)(n0+r)*64 + c];
    }
    __syncthreads();
    u16* O = Wt + (size_t)z*1048576 + (size_t)h*64*1024 + n0;
    #pragma unroll
    for (int i=0;i<16;++i){
      int idx = t + i*256; int r2 = idx>>6, c2 = idx&63;
      O[(size_t)r2*1024 + c2] = f2hbits(tl[c2][r2]);
    }
  }
}

// ---------------- 128x128x(K=1024) NT GEMM, fp16 MFMA ----------------
// Staging via global_load_lds width=16 (async direct-to-LDS, m97 schedule).
// EPI==0 epilogue writes Q/K/V in MFMA-FRAGMENT-PACKED layout; Q pre-scaled
// by 0.125*log2(e) (attention softmax runs in log2 domain).
template<int EPI>
__launch_bounds__(256, 2)
__global__ void gemm_nt(const u16* __restrict__ A, const u16* __restrict__ Bbase,
                        const float* __restrict__ bias0, const float* __restrict__ bias1,
                        const float* __restrict__ bias2,
                        u16* __restrict__ out0, u16* __restrict__ out1, u16* __restrict__ out2,
                        float* __restrict__ fout){
  __shared__ __align__(16) u16 lds[16384];
  const int K = 1024;
  int mt = blockIdx.x, ntile = blockIdx.y, z = blockIdx.z;
  int m0 = mt*128, n0 = ntile*128;
  const u16* Ap = A;
  const u16* Bp = (EPI==0) ? (Bbase + (size_t)z*1048576) : (Bbase + (size_t)z*2097152);
  int t = threadIdx.x;
  int lane = t & 63, wv = t>>6, g = lane>>4, q15 = lane&15;
  int wr = wv>>1, wc = wv&1;

  fx4 zero4 = {0.f,0.f,0.f,0.f};
  fx4 acc[4][4];
  #pragma unroll
  for (int i=0;i<4;++i)
    #pragma unroll
    for (int j=0;j<4;++j) acc[i][j] = zero4;

  int rowA = t>>2, col8 = (t&3)*8;
  const u16* gA0 = Ap + (size_t)(m0+rowA)*K + col8;
  const u16* gA1 = Ap + (size_t)(m0+rowA+64)*K + col8;
  const u16* gB0 = Bp + (size_t)(n0+rowA)*K + col8;
  const u16* gB1 = Bp + (size_t)(n0+rowA+64)*K + col8;
  int cur = 0;

#if HAS_GLL
  u16* st = lds + wv*512;         // wave-uniform region base (HW adds lane*16B)
  {
    gll16(gA0, st);
    gll16(gA1, st + 2048);
    gll16(gB0, st + 4096);
    gll16(gB1, st + 6144);
  }
  for (int kt=0; kt<32; ++kt){
    __syncthreads();              // drains vmcnt: buf[cur] ready
    if (kt+1 < 32){
      int k0 = (kt+1)*32;
      u16* nb = st + (cur^1)*8192;
      gll16(gA0 + k0, nb);
      gll16(gA1 + k0, nb + 2048);
      gll16(gB0 + k0, nb + 4096);
      gll16(gB1 + k0, nb + 6144);
    }
    const u16* bufA = lds + cur*8192;
    const u16* bufB = bufA + 4096;
    h8 af[4], bf[4];
    #pragma unroll
    for (int f=0; f<4; ++f)
      af[f] = *(const h8*)(bufA + (wr*64 + f*16 + q15)*32 + g*8);
    #pragma unroll
    for (int f=0; f<4; ++f)
      bf[f] = *(const h8*)(bufB + (wc*64 + f*16 + q15)*32 + g*8);
    #pragma unroll
    for (int i=0;i<4;++i)
      #pragma unroll
      for (int j=0;j<4;++j)
        acc[i][j] = MFMA16(af[i], bf[j], acc[i][j]);
    cur ^= 1;
  }
#else
  s16x8 sa0 = *(const s16x8*)(gA0);
  s16x8 sa1 = *(const s16x8*)(gA1);
  s16x8 sb0 = *(const s16x8*)(gB0);
  s16x8 sb1 = *(const s16x8*)(gB1);
  *(s16x8*)(lds + t*8)        = sa0;
  *(s16x8*)(lds + 2048 + t*8) = sa1;
  *(s16x8*)(lds + 4096 + t*8) = sb0;
  *(s16x8*)(lds + 6144 + t*8) = sb1;
  for (int kt=0; kt<32; ++kt){
    if (kt+1 < 32){
      int k0 = (kt+1)*32;
      sa0 = *(const s16x8*)(gA0 + k0);
      sa1 = *(const s16x8*)(gA1 + k0);
      sb0 = *(const s16x8*)(gB0 + k0);
      sb1 = *(const s16x8*)(gB1 + k0);
    }
    __syncthreads();
    const u16* bufA = lds + cur*8192;
    const u16* bufB = bufA + 4096;
    h8 af[4], bf[4];
    #pragma unroll
    for (int f=0; f<4; ++f)
      af[f] = *(const h8*)(bufA + (wr*64 + f*16 + q15)*32 + g*8);
    #pragma unroll
    for (int f=0; f<4; ++f)
      bf[f] = *(const h8*)(bufB + (wc*64 + f*16 + q15)*32 + g*8);
    #pragma unroll
    for (int i=0;i<4;++i)
      #pragma unroll
      for (int j=0;j<4;++j)
        acc[i][j] = MFMA16(af[i], bf[j], acc[i][j]);
    if (kt+1 < 32){
      u16* nb = lds + (cur^1)*8192;
      *(s16x8*)(nb + t*8)        = sa0;
      *(s16x8*)(nb + 2048 + t*8) = sa1;
      *(s16x8*)(nb + 4096 + t*8) = sb0;
      *(s16x8*)(nb + 6144 + t*8) = sb1;
      cur ^= 1;
    }
  }
#endif

  if constexpr (EPI==0){
    const float* bias = (z==0)?bias0:((z==1)?bias1:bias2);
    float bcol[4];
    #pragma unroll
    for (int fj=0;fj<4;++fj) bcol[fj] = bias[n0 + wc*64 + fj*16 + q15];
    int bb = m0 >> 11;            // batch (tiles never cross batch)
    int s_base = (m0 & 2047) + wr*64;
    if (z < 2){
      u16* o = (z==0)? out0 : out1;
      float sc = (z==0)? 0.180336880f : 1.0f;   // Q: 0.125 * log2(e)
      #pragma unroll
      for (int fi=0;fi<4;++fi)
        #pragma unroll
        for (int fj=0;fj<4;++fj){
          int n = n0 + wc*64 + fj*16 + q15;
          int hh = n>>6, d = n&63;
          int sf = d>>4, h2i = (d>>3)&1, j = d&7;
          size_t base = ((size_t)(bb*16+hh)<<17);
          #pragma unroll
          for (int r=0;r<4;++r){
            int s = s_base + fi*16 + g*4 + r;
            int kt2 = s>>5, l = s&31;
            float v = (acc[fi][fj][r] + bcol[fj]) * sc;
            o[base + (((size_t)((kt2*8 + sf*2 + h2i)*32 + l))<<3) + j] = f2hbits(v);
          }
        }
    } else {
      // V fragment-packed
      #pragma unroll
      for (int fi=0;fi<4;++fi)
        #pragma unroll
        for (int fj=0;fj<4;++fj){
          int n = n0 + wc*64 + fj*16 + q15;
          int hh = n>>6, d = n&63;
          size_t base = ((size_t)(bb*16+hh)<<17);
          int kt2 = (s_base + fi*16)>>5;
          int tt = fi & 1;
          int h2v = g>>1;
          int jv = (g&1)*4;
          ushort4 pk;
          pk.x = f2hbits(acc[fi][fj][0] + bcol[fj]);
          pk.y = f2hbits(acc[fi][fj][1] + bcol[fj]);
          pk.z = f2hbits(acc[fi][fj][2] + bcol[fj]);
          pk.w = f2hbits(acc[fi][fj][3] + bcol[fj]);
          *(ushort4*)(out2 + base + (((size_t)((kt2*4 + tt*2 + h2v)*64 + d))<<3) + jv) = pk;
        }
    }
  } else {
    int bb = z;
    float brow[4][4];
    #pragma unroll
    for (int fi=0;fi<4;++fi)
      #pragma unroll
      for (int r=0;r<4;++r) brow[fi][r] = bias0[m0 + wr*64 + fi*16 + g*4 + r];
    #pragma unroll
    for (int fi=0;fi<4;++fi)
      #pragma unroll
      for (int fj=0;fj<4;++fj){
        int scol = n0 + wc*64 + fj*16 + q15;
        #pragma unroll
        for (int r=0;r<4;++r){
          int orow = m0 + wr*64 + fi*16 + g*4 + r;
          fout[((size_t)bb<<21) + ((size_t)orow<<11) + scol] = acc[fi][fj][r] + brow[fi][r];
        }
      }
  }
}

// ---------------- flash attention, 32x32 swapped, split-KV in-block ----------
// (round-13 best configuration, verbatim)
// 512-thr blocks: 8 waves = 4 q-tile pairs. Waves (2p, 2p+1) share q-rows
// [qb*128+p*32, +32); wave half=wv&1 sweeps KV tiles [half*32, half*32+32).
// Fixed-max softmax => partials combine LINEARLY: O=Oa+Ob, l=la+lb -- one
// 32KB LDS exchange + one __syncthreads at block end, no rescale.
__launch_bounds__(512)
__global__ void attn_kernel(const u16* __restrict__ Qb, const u16* __restrict__ Kb,
                            const u16* __restrict__ Vt, u16* __restrict__ Ob){
  __shared__ float sO[4][32][64];   // odd-wave partial O   (32 KB)
  __shared__ float sL[4][64];       // odd-wave partial l   (1 KB)
  int bid = blockIdx.x;
  int g63 = bid & 63, qb = bid >> 6;     // qb in 0..15
  int b = g63 >> 4, h = g63 & 15;
  int t = threadIdx.x;
  int lane = t & 63, wv = t >> 6;        // wv in 0..7
  int pair = wv >> 1, half = wv & 1;
  int l31 = lane&31, hi = lane>>5;
  size_t bh = (size_t)(b*16 + h);
  const u16* Qp = Qb + (bh<<17);   // fragment-packed
  const u16* Kp = Kb + (bh<<17);
  const u16* Vp = Vt + (bh<<17);
  int q0 = qb*128 + pair*32;
  int qt = qb*4 + pair;            // q0>>5
  const float NML2E = -5.77078016f;   // -4*log2(e): fixed-max shift (log2 units)

  // Q fragments (B-operand): col=q=lane&31, k = s*16 + hi*8 + j
  h8 qf[4];
  #pragma unroll
  for (int s=0;s<4;++s)
    qf[s] = *(const h8*)(Qp + (((size_t)((qt*8 + s*2 + hi)*32 + l31))<<3));

  f32x16 o0, o1, sinit;
  #pragma unroll
  for (int i=0;i<16;++i){ o0[i]=0.f; o1[i]=0.f; sinit[i]=NML2E; }
  float l_run = 0.f;

  // this wave's KV half: 32 tiles, starting at tile half*32 (65536 u16 offset)
  const u16* kc = Kp + half*65536 + (hi*256 + l31*8);
  const u16* vc = Vp + half*65536 + (hi*512 + l31*8);

  auto LOADKV = [&](const u16* kp, const u16* vp, h8 (&kf_)[4], h8 (&vf_)[4]) {
    kf_[0] = *(const h8*)(kp);
    kf_[1] = *(const h8*)(kp + 512);
    kf_[2] = *(const h8*)(kp + 1024);
    kf_[3] = *(const h8*)(kp + 1536);
    vf_[0] = *(const h8*)(vp);
    vf_[1] = *(const h8*)(vp + 256);
    vf_[2] = *(const h8*)(vp + 1024);
    vf_[3] = *(const h8*)(vp + 1280);
  };

  auto TILE = [&](h8 (&kf_)[4], h8 (&vf_)[4]) {
    __builtin_amdgcn_s_setprio(1);
    f32x16 S = MFMA32(kf_[0], qf[0], sinit);   // C-operand carries the shift
    S = MFMA32(kf_[1], qf[1], S);
    S = MFMA32(kf_[2], qf[2], S);
    S = MFMA32(kf_[3], qf[3], S);
    __builtin_amdgcn_s_setprio(0);
    // S[i]: kv = (i&3) + 8*(i>>2) + 4*hi (local), q = lane&31, log2 units

    float p[16];
    #pragma unroll
    for (int i=0;i<16;++i) p[i] = EXP2(S[i]);

    #pragma unroll
    for (int tt=0; tt<2; ++tt){
      uint32_t A0 = pkh(p[8*tt+0], p[8*tt+1]);
      uint32_t A1 = pkh(p[8*tt+2], p[8*tt+3]);
      uint32_t B0 = pkh(p[8*tt+4], p[8*tt+5]);
      uint32_t B1 = pkh(p[8*tt+6], p[8*tt+7]);
      l_run = dot2h(A0, dot2h(A1, dot2h(B0, dot2h(B1, l_run))));
      union { uint32_t u[4]; h8 v; } pf;
#if __has_builtin(__builtin_amdgcn_permlane32_swap)
      u32x2 rx = __builtin_amdgcn_permlane32_swap(A0, B0, false, false);
      u32x2 ry = __builtin_amdgcn_permlane32_swap(A1, B1, false, false);
      pf.u[0] = rx[0]; pf.u[1] = ry[0]; pf.u[2] = rx[1]; pf.u[3] = ry[1];
#else
      uint32_t s0 = hi ? A0 : B0, s1 = hi ? A1 : B1;
      uint32_t r0 = __shfl_xor(s0, 32), r1 = __shfl_xor(s1, 32);
      pf.u[0] = hi ? r0 : A0;
      pf.u[1] = hi ? r1 : A1;
      pf.u[2] = hi ? B0 : r0;
      pf.u[3] = hi ? B1 : r1;
#endif
      __builtin_amdgcn_s_setprio(1);
      if (tt == 0){
        o0 = MFMA32(vf_[0], pf.v, o0);
        o1 = MFMA32(vf_[1], pf.v, o1);
      } else {
        o0 = MFMA32(vf_[2], pf.v, o0);
        o1 = MFMA32(vf_[3], pf.v, o1);
      }
      __builtin_amdgcn_s_setprio(0);
    }
  };

  h8 kfA[4], vfA[4], kfB[4], vfB[4];
  LOADKV(kc, vc, kfA, vfA);
  for (int kt=0; kt<32; kt+=2){
    LOADKV(kc+2048, vc+2048, kfB, vfB);
    TILE(kfA, vfA);
    if (kt+2 < 32) LOADKV(kc+4096, vc+4096, kfA, vfA);
    kc += 4096; vc += 4096;
    TILE(kfB, vfB);
  }

  // ---- split-KV combine: odd wave -> LDS; even wave adds, normalizes, stores
  if (half){
    #pragma unroll
    for (int i=0;i<16;++i){
      sO[pair][i][lane]    = o0[i];
      sO[pair][16+i][lane] = o1[i];
    }
    sL[pair][lane] = l_run;
  }
  __syncthreads();
  if (!half){
    #pragma unroll
    for (int i=0;i<16;++i){
      o0[i] += sO[pair][i][lane];
      o1[i] += sO[pair][16+i][lane];
    }
    l_run += sL[pair][lane];
    // cross-half l combine (lane hi halves own disjoint kv), once
    float l_tot = l_run + __shfl_xor(l_run, 32);
    float linv = 1.f / l_tot;
    // o{0,1}[i]: d = 32*dt + (i&3) + 8*(i>>2) + 4*hi ; q = lane&31
    u16* obase = Ob + ((size_t)(b*2048 + q0 + l31))*1024 + h*64 + hi*4;
    #pragma unroll
    for (int u=0; u<4; ++u){
      ushort4 w0, w1;
      w0.x = f2hbits(o0[4*u+0]*linv); w0.y = f2hbits(o0[4*u+1]*linv);
      w0.z = f2hbits(o0[4*u+2]*linv); w0.w = f2hbits(o0[4*u+3]*linv);
      w1.x = f2hbits(o1[4*u+0]*linv); w1.y = f2hbits(o1[4*u+1]*linv);
      w1.z = f2hbits(o1[4*u+2]*linv); w1.w = f2hbits(o1[4*u+3]*linv);
      *(ushort4*)(obase + u*8)      = w0;
      *(ushort4*)(obase + 32 + u*8) = w1;
    }
  }
}

extern "C" void kernel_launch(void* const* d_in, const int* in_sizes, int n_in,
                              void* d_out, int out_size, void* d_ws, size_t ws_size,
                              hipStream_t stream) {
  const float* x    = (const float*)d_in[0];
  const float* Wq   = (const float*)d_in[1];
  const float* bq   = (const float*)d_in[2];
  const float* Wk   = (const float*)d_in[3];
  const float* bk   = (const float*)d_in[4];
  const float* Wv   = (const float*)d_in[5];
  const float* bv   = (const float*)d_in[6];
  const float* WO_w = (const float*)d_in[7];
  const float* WO_b = (const float*)d_in[8];

  char* ws = (char*)d_ws;
  u16* x16  = (u16*)(ws);
  u16* Wt   = (u16*)(ws + 16777216);
  u16* WO16 = (u16*)(ws + 23068672);
  u16* Qb   = (u16*)(ws + 25165824);
  u16* Kb   = (u16*)(ws + 41943040);
  u16* Vtb  = (u16*)(ws + 58720256);
  u16* Ob   = (u16*)(ws + 75497472);

  prep_kernel<<<9984, 256, 0, stream>>>(x, x16, WO_w, WO16, Wq, Wk, Wv, Wt);
  gemm_nt<0><<<dim3(64,8,3), 256, 0, stream>>>(x16, Wt, bq, bk, bv, Qb, Kb, Vtb, nullptr);
  attn_kernel<<<1024, 512, 0, stream>>>(Qb, Kb, Vtb, Ob);
  gemm_nt<1><<<dim3(8,16,4), 256, 0, stream>>>(WO16, Ob, WO_b, nullptr, nullptr,
                                               nullptr, nullptr, nullptr, (float*)d_out);
}